// Round 1
// baseline (11981.019 us; speedup 1.0000x reference)
//
#include <hip/hip_runtime.h>
#include <hip/hip_bf16.h>

typedef float  f32x4  __attribute__((ext_vector_type(4)));
typedef short  short8 __attribute__((ext_vector_type(8)));

#define MFMA16(a,b,c) __builtin_amdgcn_mfma_f32_16x16x32_bf16((a),(b),(c),0,0,0)

__device__ __forceinline__ short tobf(float f){
  unsigned u = __float_as_uint(f);
  u += 0x7fffu + ((u >> 16) & 1u);
  return (short)(u >> 16);
}
__device__ __forceinline__ float frombf(short s){
  return __uint_as_float(((unsigned)(unsigned short)s) << 16);
}
__device__ __forceinline__ float sigf(float x){
  return 1.f / (1.f + __expf(-x));
}
__device__ __forceinline__ float tanhf_(float x){
  float ax = fabsf(x);
  float e  = __expf(-2.f * ax);
  float t  = (1.f - e) / (1.f + e);
  return x >= 0.f ? t : -t;
}

// LDS h-tile: [32 rows][256 cols] bf16, XOR-swizzled 16B slots to avoid
// 32-way bank conflicts on stride-512B ds_read_b128 (G4).
__device__ __forceinline__ int hoff(int row, int col){
  return (row*512 + col*2) ^ ((row & 7) << 4);
}
__device__ __forceinline__ void stH(short* buf, int row, int col, short v){
  *(short*)((char*)buf + hoff(row,col)) = v;
}
__device__ __forceinline__ short ldH(const short* buf, int row, int col){
  return *(const short*)((const char*)buf + hoff(row,col));
}
// A-fragment (16x32 tile): lane holds A[row=l&15][k0 + (l>>4)*8 + j]
__device__ __forceinline__ short8 ldA(const short* buf, int rt, int k0, int lane){
  int row = rt*16 + (lane & 15);
  int off = (row*512 + (k0 + ((lane>>4)<<3))*2) ^ ((row & 7) << 4);
  return *(const short8*)((const char*)buf + off);
}
// B-fragment from pre-swizzled weights: 1KB per (nt,kt) tile, lane-contiguous
__device__ __forceinline__ short8 ldB(const short* wsz, int nt, int KT, int kt, int lane){
  return *(const short8*)(wsz + (((nt*KT + kt)*64 + lane) << 3));
}

// Pre-swizzle fp32 weight [N][K] slice into bf16 B-fragments:
// frag elem (lane l, j) = W[nt*16 + (l&15)][kt*32 + (l>>4)*8 + j]
__global__ void swz_kernel(short* __restrict__ dst, const float* __restrict__ src,
                           int rowStride, int colOff, int Nreal,
                           int KTtot, int kt0, int ktN, int NT){
  int idx = blockIdx.x*256 + threadIdx.x;
  if (idx >= NT*ktN*512) return;
  int j = idx & 7, l = (idx>>3) & 63, tile = idx >> 9;
  int nt = tile / ktN, ktl = tile - nt*ktN;
  int n = nt*16 + (l & 15);
  int k = ktl*32 + ((l>>4)<<3) + j;
  float v = (n < Nreal) ? src[n*rowStride + colOff + k] : 0.f;
  dst[(((nt*KTtot + kt0 + ktl)*64 + l)<<3) + j] = tobf(v);
}

// eproj[s][v][g] = emb[s][v] @ W1_ih[s][:, :256].T + b1_ih[s] + b1_hh[s]
__global__ __launch_bounds__(1024) void eproj_kernel(
    const float* __restrict__ emb, const float* __restrict__ b1_ih,
    const float* __restrict__ b1_hh, const short* __restrict__ W1ihA_s,
    float* __restrict__ eproj){
  __shared__ short es[36864];     // [144][256] bf16, rows >=130 zero
  const int s = blockIdx.x;
  const int tid = threadIdx.x, lane = tid & 63, w = tid >> 6;
  const int l15 = lane & 15, lg = lane >> 4;
  for (int idx = tid; idx < 36864; idx += 1024){
    int row = idx >> 8, c2 = idx & 255;
    float v = (row < 130) ? emb[(s*130 + row)*256 + c2] : 0.f;
    stH(es, row, c2, tobf(v));
  }
  __syncthreads();
  f32x4 z4 = {0.f,0.f,0.f,0.f};
  for (int rt = 0; rt < 9; ++rt){
    f32x4 acc[4] = {z4, z4, z4, z4};
    #pragma unroll 2
    for (int kt = 0; kt < 8; ++kt){
      short8 a = ldA(es, rt, kt*32, lane);
      #pragma unroll
      for (int q = 0; q < 4; ++q){
        short8 b = ldB(W1ihA_s + s*262144, w*4 + q, 8, kt, lane);
        acc[q] = MFMA16(a, b, acc[q]);
      }
    }
    #pragma unroll
    for (int q = 0; q < 4; ++q)
      #pragma unroll
      for (int r = 0; r < 4; ++r){
        int v = rt*16 + lg*4 + r;
        if (v < 130){
          int gc = (w*4 + q)*16 + l15;
          eproj[(s*130 + v)*1024 + gc] = acc[q][r] + b1_ih[s*1024 + gc] + b1_hh[s*1024 + gc];
        }
      }
  }
}

// Main persistent kernel: one WG per (bar, batch-chunk-of-32). 512 threads.
__global__ __launch_bounds__(512, 2) void rnn_main(
    const float* __restrict__ cbuf, const int* __restrict__ tgt,
    const float* __restrict__ b_hid, const float* __restrict__ b1_ih,
    const float* __restrict__ b1_hh, const float* __restrict__ bc_ih,
    const float* __restrict__ bc_hh, const float* __restrict__ boutp,
    const float* __restrict__ eproj, short* __restrict__ cpart,
    const short* __restrict__ W1hh_s, const short* __restrict__ W1ihA_s,
    const short* __restrict__ W1ihB_s, const short* __restrict__ Wc_s,
    const short* __restrict__ Whid_s, const short* __restrict__ Wout_s,
    float* __restrict__ outp)
{
  __shared__ short h1b[3][8192];
  __shared__ short h2b[3][8192];
  __shared__ short hcb[8192];
  __shared__ short hsb[8192];     // scratch: c staging at reset, h1+h2 otherwise

  const int tid  = threadIdx.x;
  const int lane = tid & 63;
  const int w    = tid >> 6;      // wave 0..7; owns hidden blocks w and w+8
  const int l15  = lane & 15;
  const int lg   = lane >> 4;
  const int chunk = blockIdx.x;   // 0..3
  const int bar   = blockIdx.y;   // 0..15
  const int b0    = chunk * 32;

  float c1s[3][2][2][4];          // [stream][hb][rt][r]
  float c2s[3][2][2][4];
  float ccs[2][2][4];

  short* cpWG = cpart + ((bar*4 + chunk)*3) * 32 * 1024;
  const f32x4 z4 = {0.f,0.f,0.f,0.f};

  for (int tt = 0; tt < 16; ++tt){
    const int t = bar*16 + tt;

    if (tt == 0){
      // R1: stage bf16(c[:,bar]) into hsb
      for (int idx = tid; idx < 8192; idx += 512){
        int row = idx >> 8, cc = idx & 255;
        stH(hsb, row, cc, tobf(cbuf[((b0+row)*17 + bar)*256 + cc]));
      }
      __syncthreads();
      // R2K: h_init = tanh(c_bar @ W_hid[:256].T + b_hid[:256])
      f32x4 hi00 = z4, hi01 = z4, hi10 = z4, hi11 = z4;
      #pragma unroll 2
      for (int kt = 0; kt < 8; ++kt){
        short8 a0 = ldA(hsb, 0, kt*32, lane);
        short8 a1 = ldA(hsb, 1, kt*32, lane);
        short8 bb0 = ldB(Whid_s, w,     8, kt, lane);
        short8 bb1 = ldB(Whid_s, w + 8, 8, kt, lane);
        hi00 = MFMA16(a0, bb0, hi00);  hi01 = MFMA16(a1, bb0, hi01);
        hi10 = MFMA16(a0, bb1, hi10);  hi11 = MFMA16(a1, bb1, hi11);
      }
      __syncthreads();
      // R2elem: write h_init into all 7 h-buffers; zero c-states. Then R3.
      #pragma unroll
      for (int h = 0; h < 2; ++h){
        int cc = (h ? w+8 : w)*16 + l15;
        float bh = b_hid[cc];
        #pragma unroll
        for (int rt = 0; rt < 2; ++rt)
          #pragma unroll
          for (int r = 0; r < 4; ++r){
            int row = rt*16 + lg*4 + r;
            float v = (h==0) ? (rt ? hi01[r] : hi00[r]) : (rt ? hi11[r] : hi10[r]);
            short hv = tobf(tanhf_(v + bh));
            stH(h1b[0],row,cc,hv); stH(h1b[1],row,cc,hv); stH(h1b[2],row,cc,hv);
            stH(h2b[0],row,cc,hv); stH(h2b[1],row,cc,hv); stH(h2b[2],row,cc,hv);
            stH(hcb,  row,cc,hv);
          }
      }
      #pragma unroll
      for (int s = 0; s < 3; ++s)
        #pragma unroll
        for (int h = 0; h < 2; ++h)
          #pragma unroll
          for (int rt = 0; rt < 2; ++rt)
            #pragma unroll
            for (int r = 0; r < 4; ++r){ c1s[s][h][rt][r] = 0.f; c2s[s][h][rt][r] = 0.f; }
      #pragma unroll
      for (int h = 0; h < 2; ++h)
        #pragma unroll
        for (int rt = 0; rt < 2; ++rt)
          #pragma unroll
          for (int r = 0; r < 4; ++r) ccs[h][rt][r] = 0.f;
      // R3: stage bf16(c[:,bar+1]) into hsb
      for (int idx = tid; idx < 8192; idx += 512){
        int row = idx >> 8, cc = idx & 255;
        stH(hsb, row, cc, tobf(cbuf[((b0+row)*17 + bar + 1)*256 + cc]));
      }
      __syncthreads();
      // R4: cpart[s] = c_t @ W1_ih[s][:,256:].T  (bf16 in global ws)
      #pragma unroll
      for (int s = 0; s < 3; ++s){
        f32x4 acc[2][2][4];
        #pragma unroll
        for (int h = 0; h < 2; ++h)
          #pragma unroll
          for (int rt = 0; rt < 2; ++rt)
            #pragma unroll
            for (int g = 0; g < 4; ++g) acc[h][rt][g] = z4;
        #pragma unroll 2
        for (int kt = 0; kt < 8; ++kt){
          short8 a0 = ldA(hsb, 0, kt*32, lane);
          short8 a1 = ldA(hsb, 1, kt*32, lane);
          #pragma unroll
          for (int h = 0; h < 2; ++h){
            const int hb = h ? w+8 : w;
            #pragma unroll
            for (int g = 0; g < 4; ++g){
              short8 bb = ldB(W1ihB_s + s*262144, g*16 + hb, 8, kt, lane);
              acc[h][0][g] = MFMA16(a0, bb, acc[h][0][g]);
              acc[h][1][g] = MFMA16(a1, bb, acc[h][1][g]);
            }
          }
        }
        #pragma unroll
        for (int h = 0; h < 2; ++h){
          int cc = (h ? w+8 : w)*16 + l15;
          #pragma unroll
          for (int rt = 0; rt < 2; ++rt)
            #pragma unroll
            for (int r = 0; r < 4; ++r){
              int row = rt*16 + lg*4 + r;
              short* cp = cpWG + (s*32 + row)*1024;
              #pragma unroll
              for (int g = 0; g < 4; ++g) cp[g*256 + cc] = tobf(acc[h][rt][g][r]);
            }
        }
      }
      // no sync needed: h1b writes already fenced by post-R3 barrier
    }

    // ---------- Stage A: lstm1 first update, per stream ----------
    #pragma unroll
    for (int s = 0; s < 3; ++s){
      f32x4 acc[2][2][4];
      #pragma unroll
      for (int h = 0; h < 2; ++h)
        #pragma unroll
        for (int rt = 0; rt < 2; ++rt)
          #pragma unroll
          for (int g = 0; g < 4; ++g) acc[h][rt][g] = z4;
      #pragma unroll 2
      for (int kt = 0; kt < 8; ++kt){
        short8 a0 = ldA(h1b[s], 0, kt*32, lane);
        short8 a1 = ldA(h1b[s], 1, kt*32, lane);
        #pragma unroll
        for (int h = 0; h < 2; ++h){
          const int hb = h ? w+8 : w;
          #pragma unroll
          for (int g = 0; g < 4; ++g){
            short8 bb = ldB(W1hh_s + s*262144, g*16 + hb, 8, kt, lane);
            acc[h][0][g] = MFMA16(a0, bb, acc[h][0][g]);
            acc[h][1][g] = MFMA16(a1, bb, acc[h][1][g]);
          }
        }
      }
      __syncthreads();
      #pragma unroll
      for (int rt = 0; rt < 2; ++rt)
        #pragma unroll
        for (int r = 0; r < 4; ++r){
          const int row = rt*16 + lg*4 + r;
          const int tok = (t == 0) ? 0 : tgt[(s*128 + b0 + row)*256 + (t-1)];
          const float* ep = eproj + (s*130 + tok)*1024;
          const short* cp = cpWG + (s*32 + row)*1024;
          #pragma unroll
          for (int h = 0; h < 2; ++h){
            const int cc = (h ? w+8 : w)*16 + l15;
            float pi = acc[h][rt][0][r] + ep[cc]       + frombf(cp[cc]);
            float pf = acc[h][rt][1][r] + ep[256+cc]   + frombf(cp[256+cc]);
            float pg = acc[h][rt][2][r] + ep[512+cc]   + frombf(cp[512+cc]);
            float po = acc[h][rt][3][r] + ep[768+cc]   + frombf(cp[768+cc]);
            float cs = c1s[s][h][rt][r];
            cs = sigf(pf)*cs + sigf(pi)*tanhf_(pg);
            c1s[s][h][rt][r] = cs;
            stH(h1b[s], row, cc, tobf(sigf(po)*tanhf_(cs)));
          }
        }
      __syncthreads();
    }

    // ---------- per-stream sequential section ----------
    #pragma unroll
    for (int i = 0; i < 3; ++i){
      // ---- B: context lstm_c
      {
        f32x4 acc[2][2][4];
        #pragma unroll
        for (int h = 0; h < 2; ++h)
          #pragma unroll
          for (int rt = 0; rt < 2; ++rt)
            #pragma unroll
            for (int g = 0; g < 4; ++g) acc[h][rt][g] = z4;
        #pragma unroll
        for (int seg = 0; seg < 4; ++seg){
          const short* hbuf = (seg==0) ? h1b[0] : (seg==1) ? h1b[1] : (seg==2) ? h1b[2] : hcb;
          #pragma unroll 2
          for (int ktl = 0; ktl < 8; ++ktl){
            const int kt = seg*8 + ktl;
            short8 a0 = ldA(hbuf, 0, ktl*32, lane);
            short8 a1 = ldA(hbuf, 1, ktl*32, lane);
            #pragma unroll
            for (int h = 0; h < 2; ++h){
              const int hb = h ? w+8 : w;
              #pragma unroll
              for (int g = 0; g < 4; ++g){
                short8 bb = ldB(Wc_s, g*16 + hb, 32, kt, lane);
                acc[h][0][g] = MFMA16(a0, bb, acc[h][0][g]);
                acc[h][1][g] = MFMA16(a1, bb, acc[h][1][g]);
              }
            }
          }
        }
        __syncthreads();
        #pragma unroll
        for (int h = 0; h < 2; ++h){
          const int cc = (h ? w+8 : w)*16 + l15;
          const float bi = bc_ih[cc]      + bc_hh[cc];
          const float bf = bc_ih[256+cc]  + bc_hh[256+cc];
          const float bg = bc_ih[512+cc]  + bc_hh[512+cc];
          const float bo = bc_ih[768+cc]  + bc_hh[768+cc];
          #pragma unroll
          for (int rt = 0; rt < 2; ++rt)
            #pragma unroll
            for (int r = 0; r < 4; ++r){
              const int row = rt*16 + lg*4 + r;
              float pi = acc[h][rt][0][r] + bi;
              float pf = acc[h][rt][1][r] + bf;
              float pg = acc[h][rt][2][r] + bg;
              float po = acc[h][rt][3][r] + bo;
              float cs = ccs[h][rt][r];
              cs = sigf(pf)*cs + sigf(pi)*tanhf_(pg);
              ccs[h][rt][r] = cs;
              stH(hcb, row, cc, tobf(sigf(po)*tanhf_(cs)));
            }
        }
        __syncthreads();
      }
      // ---- C: lstm2 + (h1+h2) into hsb
      {
        f32x4 acc[2][2][4];
        #pragma unroll
        for (int h = 0; h < 2; ++h)
          #pragma unroll
          for (int rt = 0; rt < 2; ++rt)
            #pragma unroll
            for (int g = 0; g < 4; ++g) acc[h][rt][g] = z4;
        #pragma unroll 2
        for (int kt = 0; kt < 8; ++kt){
          short8 a0 = ldA(hcb, 0, kt*32, lane);
          short8 a1 = ldA(hcb, 1, kt*32, lane);
          #pragma unroll
          for (int h = 0; h < 2; ++h){
            const int hb = h ? w+8 : w;
            #pragma unroll
            for (int g = 0; g < 4; ++g){
              short8 bb = ldB(W1ihA_s + i*262144, g*16 + hb, 8, kt, lane);
              acc[h][0][g] = MFMA16(a0, bb, acc[h][0][g]);
              acc[h][1][g] = MFMA16(a1, bb, acc[h][1][g]);
            }
          }
        }
        #pragma unroll 2
        for (int kt = 0; kt < 8; ++kt){
          short8 a0 = ldA(h2b[i], 0, kt*32, lane);
          short8 a1 = ldA(h2b[i], 1, kt*32, lane);
          #pragma unroll
          for (int h = 0; h < 2; ++h){
            const int hb = h ? w+8 : w;
            #pragma unroll
            for (int g = 0; g < 4; ++g){
              short8 bb = ldB(W1hh_s + i*262144, g*16 + hb, 8, kt, lane);
              acc[h][0][g] = MFMA16(a0, bb, acc[h][0][g]);
              acc[h][1][g] = MFMA16(a1, bb, acc[h][1][g]);
            }
          }
        }
        __syncthreads();
        #pragma unroll
        for (int h = 0; h < 2; ++h){
          const int cc = (h ? w+8 : w)*16 + l15;
          const float bi = b1_ih[i*1024+cc]      + b1_hh[i*1024+cc];
          const float bf = b1_ih[i*1024+256+cc]  + b1_hh[i*1024+256+cc];
          const float bg = b1_ih[i*1024+512+cc]  + b1_hh[i*1024+512+cc];
          const float bo = b1_ih[i*1024+768+cc]  + b1_hh[i*1024+768+cc];
          #pragma unroll
          for (int rt = 0; rt < 2; ++rt)
            #pragma unroll
            for (int r = 0; r < 4; ++r){
              const int row = rt*16 + lg*4 + r;
              const short* cp = cpWG + (i*32 + row)*1024;
              float pi = acc[h][rt][0][r] + bi + frombf(cp[cc]);
              float pf = acc[h][rt][1][r] + bf + frombf(cp[256+cc]);
              float pg = acc[h][rt][2][r] + bg + frombf(cp[512+cc]);
              float po = acc[h][rt][3][r] + bo + frombf(cp[768+cc]);
              float cs = c2s[i][h][rt][r];
              cs = sigf(pf)*cs + sigf(pi)*tanhf_(pg);
              c2s[i][h][rt][r] = cs;
              float hn = sigf(po)*tanhf_(cs);
              stH(h2b[i], row, cc, tobf(hn));
              float h1o = frombf(ldH(h1b[i], row, cc));
              stH(hsb, row, cc, tobf(h1o + hn));
            }
        }
        __syncthreads();
      }
      // ---- ED: output projection (E) + lstm1 second update (D)
      {
        f32x4 dacc[2][2][4];
        #pragma unroll
        for (int h = 0; h < 2; ++h)
          #pragma unroll
          for (int rt = 0; rt < 2; ++rt)
            #pragma unroll
            for (int g = 0; g < 4; ++g) dacc[h][rt][g] = z4;
        #pragma unroll 2
        for (int kt = 0; kt < 8; ++kt){
          short8 a0 = ldA(h1b[i], 0, kt*32, lane);
          short8 a1 = ldA(h1b[i], 1, kt*32, lane);
          #pragma unroll
          for (int h = 0; h < 2; ++h){
            const int hb = h ? w+8 : w;
            #pragma unroll
            for (int g = 0; g < 4; ++g){
              short8 bb = ldB(W1hh_s + i*262144, g*16 + hb, 8, kt, lane);
              dacc[h][0][g] = MFMA16(a0, bb, dacc[h][0][g]);
              dacc[h][1][g] = MFMA16(a1, bb, dacc[h][1][g]);
            }
          }
        }
        f32x4 e00 = z4, e01 = z4, e10 = z4, e11 = z4;
        #pragma unroll 2
        for (int kt = 0; kt < 8; ++kt){
          short8 a0 = ldA(hsb, 0, kt*32, lane);
          short8 a1 = ldA(hsb, 1, kt*32, lane);
          short8 bb = ldB(Wout_s + i*36864, w, 8, kt, lane);
          e00 = MFMA16(a0, bb, e00);  e01 = MFMA16(a1, bb, e01);
        }
        if (w == 0){
          #pragma unroll 2
          for (int kt = 0; kt < 8; ++kt){
            short8 a0 = ldA(hsb, 0, kt*32, lane);
            short8 a1 = ldA(hsb, 1, kt*32, lane);
            short8 bb = ldB(Wout_s + i*36864, 8, 8, kt, lane);
            e10 = MFMA16(a0, bb, e10);  e11 = MFMA16(a1, bb, e11);
          }
        }
        __syncthreads();
        // D elem: teacher-forced notes update of lstm1
        #pragma unroll
        for (int rt = 0; rt < 2; ++rt)
          #pragma unroll
          for (int r = 0; r < 4; ++r){
            const int row = rt*16 + lg*4 + r;
            const int tok = tgt[(i*128 + b0 + row)*256 + t];
            const float* ep = eproj + (i*130 + tok)*1024;
            const short* cp = cpWG + (i*32 + row)*1024;
            #pragma unroll
            for (int h = 0; h < 2; ++h){
              const int cc = (h ? w+8 : w)*16 + l15;
              float pi = dacc[h][rt][0][r] + ep[cc]     + frombf(cp[cc]);
              float pf = dacc[h][rt][1][r] + ep[256+cc] + frombf(cp[256+cc]);
              float pg = dacc[h][rt][2][r] + ep[512+cc] + frombf(cp[512+cc]);
              float po = dacc[h][rt][3][r] + ep[768+cc] + frombf(cp[768+cc]);
              float cs = c1s[i][h][rt][r];
              cs = sigf(pf)*cs + sigf(pi)*tanhf_(pg);
              c1s[i][h][rt][r] = cs;
              stH(h1b[i], row, cc, tobf(sigf(po)*tanhf_(cs)));
            }
          }
        // E store: logits
        {
          const int v = w*16 + l15;    // always < 128
          const float bo = boutp[i*130 + v];
          #pragma unroll
          for (int rt = 0; rt < 2; ++rt)
            #pragma unroll
            for (int r = 0; r < 4; ++r){
              const int row = rt*16 + lg*4 + r;
              outp[(size_t)((i*128 + b0 + row)*256 + t)*130 + v] = (rt ? e01[r] : e00[r]) + bo;
            }
          if (w == 0 && l15 < 2){
            const int v2 = 128 + l15;
            const float bo2 = boutp[i*130 + v2];
            #pragma unroll
            for (int rt = 0; rt < 2; ++rt)
              #pragma unroll
              for (int r = 0; r < 4; ++r){
                const int row = rt*16 + lg*4 + r;
                outp[(size_t)((i*128 + b0 + row)*256 + t)*130 + v2] = (rt ? e11[r] : e10[r]) + bo2;
              }
          }
        }
        __syncthreads();
      }
    } // i
  } // tt
}

extern "C" void kernel_launch(void* const* d_in, const int* in_sizes, int n_in,
                              void* d_out, int out_size, void* d_ws, size_t ws_size,
                              hipStream_t stream){
  (void)in_sizes; (void)n_in; (void)out_size; (void)ws_size;
  const float* c     = (const float*)d_in[0];
  const int*   tgt   = (const int*)  d_in[1];
  const float* W_hid = (const float*)d_in[3];
  const float* b_hid = (const float*)d_in[4];
  const float* W1_ih = (const float*)d_in[5];
  const float* W1_hh = (const float*)d_in[6];
  const float* b1_ih = (const float*)d_in[7];
  const float* b1_hh = (const float*)d_in[8];
  const float* Wc_ih = (const float*)d_in[9];
  const float* Wc_hh = (const float*)d_in[10];
  const float* bc_ih = (const float*)d_in[11];
  const float* bc_hh = (const float*)d_in[12];
  const float* emb   = (const float*)d_in[13];
  const float* Wout  = (const float*)d_in[14];
  const float* bout  = (const float*)d_in[15];
  float* outp = (float*)d_out;

  short* ws = (short*)d_ws;
  short* W1hh_s  = ws;                 // 3 x 64x8 tiles
  short* W1ihA_s = ws + 786432;        // W1_ih[:, :256]
  short* W1ihB_s = ws + 1572864;       // W1_ih[:, 256:512]
  short* Wc_s    = ws + 2359296;       // [1024][1024]: ih k<768, hh k>=768
  short* Whid_s  = ws + 3407872;       // [256][256]
  short* Wout_s  = ws + 3473408;       // 3 x [144 pad][256]
  float* eproj   = (float*)(ws + 3584000);                  // [3][130][1024] f32
  short* cpart   = (short*)((char*)d_ws + 8765440);         // [16][4][3][32][1024] bf16

  for (int s = 0; s < 3; ++s){
    swz_kernel<<<1024,256,0,stream>>>(W1hh_s  + s*262144, W1_hh + s*262144, 256,   0, 1024,  8, 0,  8, 64);
    swz_kernel<<<1024,256,0,stream>>>(W1ihA_s + s*262144, W1_ih + s*524288, 512,   0, 1024,  8, 0,  8, 64);
    swz_kernel<<<1024,256,0,stream>>>(W1ihB_s + s*262144, W1_ih + s*524288, 512, 256, 1024,  8, 0,  8, 64);
    swz_kernel<<< 144,256,0,stream>>>(Wout_s  + s*36864,  Wout  + s*33280,  256,   0,  130,  8, 0,  8,  9);
  }
  swz_kernel<<<3072,256,0,stream>>>(Wc_s,   Wc_ih, 768, 0, 1024, 32,  0, 24, 64);
  swz_kernel<<<1024,256,0,stream>>>(Wc_s,   Wc_hh, 256, 0, 1024, 32, 24,  8, 64);
  swz_kernel<<< 256,256,0,stream>>>(Whid_s, W_hid, 256, 0,  512,  8,  0,  8, 16);
  eproj_kernel<<<3,1024,0,stream>>>(emb, b1_ih, b1_hh, W1ihA_s, eproj);

  rnn_main<<<dim3(4,16),512,0,stream>>>(c, tgt, b_hid, b1_ih, b1_hh, bc_ih, bc_hh,
                                        bout, eproj, cpart, W1hh_s, W1ihA_s, W1ihB_s,
                                        Wc_s, Whid_s, Wout_s, outp);
}